// Round 2
// baseline (965.633 us; speedup 1.0000x reference)
//
#include <hip/hip_runtime.h>
#include <hip/hip_bf16.h>
#include <stdint.h>

typedef unsigned short u16;
typedef __attribute__((ext_vector_type(8))) short short8;
typedef __attribute__((ext_vector_type(4))) float f32x4;

#define NB 64
#define NN 4096
#define NS 8
#define ND 256
#define GROWS (NB*NN)   // 262144

__device__ inline u16 f2bf(float f) {
    uint32_t u = __float_as_uint(f);
    u = (u + 0x7FFFu + ((u >> 16) & 1u)) >> 16;
    return (u16)u;
}
__device__ inline float bf2f(u16 h) {
    return __uint_as_float(((uint32_t)h) << 16);
}
__device__ inline f32x4 mfma16(short8 a, short8 b, f32x4 c) {
    return __builtin_amdgcn_mfma_f32_16x16x32_bf16(a, b, c, 0, 0, 0);
}

// ---------------- weight conversion fp32 -> bf16 (once per launch) ----------
__global__ __launch_bounds__(256) void prep_w(
        const float* __restrict__ wk, const float* __restrict__ wv, const float* __restrict__ wq,
        const float* __restrict__ wih, const float* __restrict__ whh,
        const float* __restrict__ w1, const float* __restrict__ w2,
        u16* __restrict__ wkvb, u16* __restrict__ wqb, u16* __restrict__ wihb,
        u16* __restrict__ whhb, u16* __restrict__ w1b, u16* __restrict__ w2b) {
    int i = blockIdx.x * 256 + threadIdx.x;
    if (i < 131072) { wkvb[i] = f2bf(i < 65536 ? wk[i] : wv[i - 65536]); return; }
    i -= 131072;
    if (i < 65536) { wqb[i] = f2bf(wq[i]); return; }
    i -= 65536;
    if (i < 196608) { wihb[i] = f2bf(wih[i]); return; }
    i -= 196608;
    if (i < 196608) { whhb[i] = f2bf(whh[i]); return; }
    i -= 196608;
    if (i < 65536) { w1b[i] = f2bf(w1[i]); return; }
    i -= 65536;
    w2b[i] = f2bf(w2[i]);
}

// ---------------- LayerNorm(inputs) -> x bf16 -------------------------------
__global__ __launch_bounds__(256) void ln_x(
        const float* __restrict__ inp, const float* __restrict__ g,
        const float* __restrict__ bt, u16* __restrict__ xb) {
    int row = blockIdx.x * 4 + (threadIdx.x >> 6);
    int lane = threadIdx.x & 63;
    float4 v = reinterpret_cast<const float4*>(inp + (size_t)row * ND)[lane];
    float s = v.x + v.y + v.z + v.w;
    float ss = v.x*v.x + v.y*v.y + v.z*v.z + v.w*v.w;
#pragma unroll
    for (int off = 32; off >= 1; off >>= 1) { s += __shfl_xor(s, off, 64); ss += __shfl_xor(ss, off, 64); }
    float mean = s * (1.0f/256.0f);
    float rstd = rsqrtf(ss * (1.0f/256.0f) - mean*mean + 1e-5f);
    float4 g4 = reinterpret_cast<const float4*>(g)[lane];
    float4 b4 = reinterpret_cast<const float4*>(bt)[lane];
    ushort4 o;
    o.x = f2bf((v.x-mean)*rstd*g4.x + b4.x);
    o.y = f2bf((v.y-mean)*rstd*g4.y + b4.y);
    o.z = f2bf((v.z-mean)*rstd*g4.z + b4.z);
    o.w = f2bf((v.w-mean)*rstd*g4.w + b4.w);
    *reinterpret_cast<ushort4*>(xb + (size_t)row * ND + lane*4) = o;
}

// ---------------- K/V projection GEMM: C = x @ [wk|wv]^T --------------------
// cols 0..255 -> k (row-major bf16), cols 256..511 -> vT[b][d][n] bf16
__global__ __launch_bounds__(256) void gemm_kv(
        const u16* __restrict__ A, const u16* __restrict__ W,
        const float* __restrict__ bk, const float* __restrict__ bv,
        u16* __restrict__ kout, u16* __restrict__ vT) {
    __shared__ u16 As[128*32];
    __shared__ u16 Bs[128*32];
    __shared__ u16 Ct[128*136];
    const int bx = blockIdx.x;
    const int nt = bx & 3;
    const long r0 = (long)(bx >> 2) * 128;
    const int o0 = nt * 128;
    const int tid = threadIdx.x;
    const int wid = tid >> 6, lane = tid & 63;
    const int l15 = lane & 15, kq = (lane >> 4) * 8;
    const int wm = (wid >> 1) * 64, wn = (wid & 1) * 64;
    f32x4 acc[4][4];
#pragma unroll
    for (int i = 0; i < 4; i++)
#pragma unroll
        for (int j = 0; j < 4; j++) acc[i][j] = (f32x4){0.f,0.f,0.f,0.f};

    // staging: 128 rows x 32 cols = 4096 bf16; 256 threads x 16 elems (2x short8)
    const int srow = tid >> 1, scol = (tid & 1) * 16;
    for (int k0 = 0; k0 < 256; k0 += 32) {
        const u16* ag = &A[(r0 + srow)*256 + k0 + scol];
        const u16* bg = &W[(long)(o0 + srow)*256 + k0 + scol];
        *reinterpret_cast<short8*>(&As[srow*32 + scol])     = *reinterpret_cast<const short8*>(ag);
        *reinterpret_cast<short8*>(&As[srow*32 + scol + 8]) = *reinterpret_cast<const short8*>(ag + 8);
        *reinterpret_cast<short8*>(&Bs[srow*32 + scol])     = *reinterpret_cast<const short8*>(bg);
        *reinterpret_cast<short8*>(&Bs[srow*32 + scol + 8]) = *reinterpret_cast<const short8*>(bg + 8);
        __syncthreads();
        short8 af[4], bfr[4];
#pragma unroll
        for (int i = 0; i < 4; i++) af[i] = *reinterpret_cast<const short8*>(&As[(wm + i*16 + l15)*32 + kq]);
#pragma unroll
        for (int j = 0; j < 4; j++) bfr[j] = *reinterpret_cast<const short8*>(&Bs[(wn + j*16 + l15)*32 + kq]);
#pragma unroll
        for (int i = 0; i < 4; i++)
#pragma unroll
            for (int j = 0; j < 4; j++)
                acc[i][j] = mfma16(af[i], bfr[j], acc[i][j]);
        __syncthreads();
    }
    if (nt < 2) {
        // k output, row-major: repack through LDS then coalesced 16B stores
#pragma unroll
        for (int i = 0; i < 4; i++)
#pragma unroll
            for (int j = 0; j < 4; j++) {
                int c = wn + j*16 + l15;
                float bb = bk[o0 + c];
                int mb = wm + i*16 + (lane >> 4)*4;
#pragma unroll
                for (int r = 0; r < 4; r++)
                    Ct[(mb + r)*136 + c] = f2bf(acc[i][j][r] + bb);
            }
        __syncthreads();
        int rr = tid >> 1, cc = (tid & 1) * 64;
#pragma unroll
        for (int u = 0; u < 64; u += 8)
            *reinterpret_cast<short8*>(&kout[(r0 + rr)*256 + o0 + cc + u]) =
                *reinterpret_cast<const short8*>(&Ct[rr*136 + cc + u]);
    } else {
        // v output, transposed to vT[b][d][n]
#pragma unroll
        for (int i = 0; i < 4; i++)
#pragma unroll
            for (int j = 0; j < 4; j++) {
                int c = wn + j*16 + l15;
                float bb = bv[o0 - 256 + c];
                int mb = wm + i*16 + (lane >> 4)*4;
                ushort4 pk;
                pk.x = f2bf(acc[i][j][0] + bb);
                pk.y = f2bf(acc[i][j][1] + bb);
                pk.z = f2bf(acc[i][j][2] + bb);
                pk.w = f2bf(acc[i][j][3] + bb);
                *reinterpret_cast<ushort4*>(&Ct[c*136 + mb]) = pk;
            }
        __syncthreads();
        int rr = tid >> 1, cc = (tid & 1) * 64;
        long b_ = r0 >> 12;
        long n0_ = r0 & 4095;
        long dg = (o0 - 256) + rr;
#pragma unroll
        for (int u = 0; u < 64; u += 8)
            *reinterpret_cast<short8*>(&vT[(b_*256 + dg)*4096 + n0_ + cc + u]) =
                *reinterpret_cast<const short8*>(&Ct[rr*136 + cc + u]);
    }
}

// ---------------- q projection: q = LN(slots)@wq^T + bq  (bf16 out) --------
__global__ __launch_bounds__(256) void q_proj(
        const float* __restrict__ slots, const u16* __restrict__ wqb,
        const float* __restrict__ bq, const float* __restrict__ gs, const float* __restrict__ bs,
        u16* __restrict__ qb) {
    __shared__ u16 sn[16*264];
    const int b = blockIdx.x;
    const int tid = threadIdx.x, wid = tid >> 6, lane = tid & 63;
    const int l15 = lane & 15, kq = (lane >> 4) * 8;
    for (int rr = wid; rr < 8; rr += 4) {
        float4 v = reinterpret_cast<const float4*>(slots + (size_t)(b*8 + rr)*256)[lane];
        float s = v.x + v.y + v.z + v.w;
        float ss = v.x*v.x + v.y*v.y + v.z*v.z + v.w*v.w;
#pragma unroll
        for (int off = 32; off >= 1; off >>= 1) { s += __shfl_xor(s, off, 64); ss += __shfl_xor(ss, off, 64); }
        float mean = s * (1.f/256.f);
        float rstd = rsqrtf(ss * (1.f/256.f) - mean*mean + 1e-5f);
        float4 g4 = reinterpret_cast<const float4*>(gs)[lane];
        float4 b4 = reinterpret_cast<const float4*>(bs)[lane];
        ushort4 o;
        o.x = f2bf((v.x-mean)*rstd*g4.x + b4.x);
        o.y = f2bf((v.y-mean)*rstd*g4.y + b4.y);
        o.z = f2bf((v.z-mean)*rstd*g4.z + b4.z);
        o.w = f2bf((v.w-mean)*rstd*g4.w + b4.w);
        *reinterpret_cast<ushort4*>(&sn[rr*264 + lane*4]) = o;
    }
    {
        ushort4 z = {0,0,0,0};
        for (int rr = 8 + wid; rr < 16; rr += 4)
            *reinterpret_cast<ushort4*>(&sn[rr*264 + lane*4]) = z;
    }
    __syncthreads();
    short8 af[8];
#pragma unroll
    for (int k = 0; k < 8; k++) af[k] = *reinterpret_cast<const short8*>(&sn[l15*264 + k*32 + kq]);
#pragma unroll
    for (int ct = 0; ct < 4; ct++) {
        int o0 = (wid*4 + ct)*16;
        f32x4 a = (f32x4){0.f,0.f,0.f,0.f};
#pragma unroll
        for (int k = 0; k < 8; k++) {
            short8 bw = *reinterpret_cast<const short8*>(&wqb[(size_t)(o0 + l15)*256 + k*32 + kq]);
            a = mfma16(af[k], bw, a);
        }
        if (lane < 32) {
            int sb = (lane >> 4)*4;
            float bb = bq[o0 + l15];
#pragma unroll
            for (int r = 0; r < 4; r++)
                qb[(size_t)(b*8 + sb + r)*256 + o0 + l15] = f2bf(a[r] + bb);
        }
    }
}

// ---------------- fused attention pass: dots -> softmax(S) -> P.V partials --
__global__ __launch_bounds__(256) void attn(
        const u16* __restrict__ qb, const u16* __restrict__ kb,
        const u16* __restrict__ vT, float* __restrict__ num, float* __restrict__ den) {
    __shared__ u16 q_lds[16*264];
    __shared__ u16 p_lds[16*72];
    const int b = blockIdx.x >> 4;
    const int n0 = (blockIdx.x & 15) * 256;
    const int tid = threadIdx.x, wid = tid >> 6, lane = tid & 63;
    const int l15 = lane & 15, kq = (lane >> 4) * 8;
    {
        int rr = tid >> 5, c8 = (tid & 31) * 8;
        *reinterpret_cast<short8*>(&q_lds[rr*264 + c8]) =
            *reinterpret_cast<const short8*>(&qb[(size_t)(b*8 + rr)*256 + c8]);
        short8 z = {0,0,0,0,0,0,0,0};
        *reinterpret_cast<short8*>(&q_lds[(8 + rr)*264 + c8]) = z;
    }
    // zero p_lds padding rows 8..15 (read as A-frag rows; outputs discarded,
    // but uninitialized LDS could hold NaN bit patterns)
    if (tid < 144) {
        int r8 = 8 + tid / 18, c4 = (tid % 18) * 4;
        ushort4 z4 = {0,0,0,0};
        *reinterpret_cast<ushort4*>(&p_lds[r8*72 + c4]) = z4;
    }
    __syncthreads();
    short8 aq[8];
#pragma unroll
    for (int k = 0; k < 8; k++) aq[k] = *reinterpret_cast<const short8*>(&q_lds[l15*264 + k*32 + kq]);
    f32x4 acc[4];
#pragma unroll
    for (int dt = 0; dt < 4; dt++) acc[dt] = (f32x4){0.f,0.f,0.f,0.f};
    float psum[4] = {0.f,0.f,0.f,0.f};
    for (int rnd = 0; rnd < 4; rnd++) {
        const int nb = n0 + rnd*64;
        const int ntile = nb + wid*16;
        f32x4 dots = (f32x4){0.f,0.f,0.f,0.f};
        const u16* krow = &kb[((size_t)b*4096 + ntile + l15)*256 + kq];
#pragma unroll
        for (int k = 0; k < 8; k++) {
            short8 bk_ = *reinterpret_cast<const short8*>(&krow[k*32]);
            dots = mfma16(aq[k], bk_, dots);
        }
        float t0 = dots[0]*0.0625f, t1 = dots[1]*0.0625f, t2 = dots[2]*0.0625f, t3 = dots[3]*0.0625f;
        float m4 = fmaxf(fmaxf(t0,t1), fmaxf(t2,t3));
        float m8 = fmaxf(m4, __shfl_xor(m4, 16, 64));
        float e0 = __expf(t0-m8), e1 = __expf(t1-m8), e2 = __expf(t2-m8), e3 = __expf(t3-m8);
        float s4 = e0+e1+e2+e3;
        float s8 = s4 + __shfl_xor(s4, 16, 64);
        float inv = 1.0f / s8;
        u16 h0 = f2bf(e0*inv + 1e-8f);
        u16 h1 = f2bf(e1*inv + 1e-8f);
        u16 h2 = f2bf(e2*inv + 1e-8f);
        u16 h3 = f2bf(e3*inv + 1e-8f);
        if (lane < 32) {
            int sb = (lane >> 4)*4;
            int col = wid*16 + l15;
            p_lds[(sb+0)*72 + col] = h0;
            p_lds[(sb+1)*72 + col] = h1;
            p_lds[(sb+2)*72 + col] = h2;
            p_lds[(sb+3)*72 + col] = h3;
            psum[0] += bf2f(h0); psum[1] += bf2f(h1);
            psum[2] += bf2f(h2); psum[3] += bf2f(h3);
        }
        __syncthreads();
        short8 ap0 = *reinterpret_cast<const short8*>(&p_lds[l15*72 + kq]);
        short8 ap1 = *reinterpret_cast<const short8*>(&p_lds[l15*72 + 32 + kq]);
#pragma unroll
        for (int dt = 0; dt < 4; dt++) {
            const u16* vrow = &vT[((size_t)b*256 + wid*64 + dt*16 + l15)*4096 + nb + kq];
            short8 b0 = *reinterpret_cast<const short8*>(&vrow[0]);
            short8 b1 = *reinterpret_cast<const short8*>(&vrow[32]);
            acc[dt] = mfma16(ap0, b0, acc[dt]);
            acc[dt] = mfma16(ap1, b1, acc[dt]);
        }
        __syncthreads();
    }
#pragma unroll
    for (int off = 1; off < 16; off <<= 1) {
#pragma unroll
        for (int r = 0; r < 4; r++) psum[r] += __shfl_xor(psum[r], off, 64);
    }
    if (lane < 32) {
        int sb = (lane >> 4)*4;
        if (l15 == 0) {
#pragma unroll
            for (int r = 0; r < 4; r++) atomicAdd(&den[b*8 + sb + r], psum[r]);
        }
#pragma unroll
        for (int dt = 0; dt < 4; dt++) {
            int d0 = wid*64 + dt*16 + l15;
#pragma unroll
            for (int r = 0; r < 4; r++)
                atomicAdd(&num[((size_t)b*8 + sb + r)*256 + d0], acc[dt][r]);
        }
    }
}

// ---------------- per-iteration tail: updates -> GRU -> MLP -> slots --------
__global__ __launch_bounds__(768) void finalize(
        const float* __restrict__ slots_in, const float* __restrict__ num, const float* __restrict__ den,
        const u16* __restrict__ wihb, const float* __restrict__ bih,
        const u16* __restrict__ whhb, const float* __restrict__ bhh,
        const u16* __restrict__ w1b, const float* __restrict__ b1v,
        const u16* __restrict__ w2b, const float* __restrict__ b2v,
        const float* __restrict__ gff, const float* __restrict__ bff,
        float* __restrict__ slots_out) {
    __shared__ u16 updb[16*264];
    __shared__ u16 prevb[16*264];
    __shared__ u16 lnb[16*264];
    __shared__ float gx[8*776];
    __shared__ float gh[8*776];
    __shared__ float snew[8*256];
    const int b = blockIdx.x;
    const int tid = threadIdx.x, wid = tid >> 6, lane = tid & 63;
    const int l15 = lane & 15, kq = (lane >> 4) * 8;
    for (int idx = tid; idx < 2048; idx += 768) {
        int s = idx >> 8, d = idx & 255;
        updb[s*264 + d] = f2bf(num[(size_t)(b*8 + s)*256 + d] / den[b*8 + s]);
        prevb[s*264 + d] = f2bf(slots_in[(size_t)(b*8 + s)*256 + d]);
        updb[(8+s)*264 + d] = 0;
        prevb[(8+s)*264 + d] = 0;
    }
    __syncthreads();
    short8 au[8], ap[8];
#pragma unroll
    for (int k = 0; k < 8; k++) {
        au[k] = *reinterpret_cast<const short8*>(&updb[l15*264 + k*32 + kq]);
        ap[k] = *reinterpret_cast<const short8*>(&prevb[l15*264 + k*32 + kq]);
    }
#pragma unroll
    for (int ct = 0; ct < 4; ct++) {
        int o0 = (wid*4 + ct)*16;
        f32x4 ax = (f32x4){0.f,0.f,0.f,0.f}, ah = (f32x4){0.f,0.f,0.f,0.f};
#pragma unroll
        for (int k = 0; k < 8; k++) {
            short8 bx = *reinterpret_cast<const short8*>(&wihb[(size_t)(o0 + l15)*256 + k*32 + kq]);
            short8 bh = *reinterpret_cast<const short8*>(&whhb[(size_t)(o0 + l15)*256 + k*32 + kq]);
            ax = mfma16(au[k], bx, ax);
            ah = mfma16(ap[k], bh, ah);
        }
        if (lane < 32) {
            int sb = (lane >> 4)*4, o = o0 + l15;
            float bxs = bih[o], bhs = bhh[o];
#pragma unroll
            for (int r = 0; r < 4; r++) {
                gx[(sb+r)*776 + o] = ax[r] + bxs;
                gh[(sb+r)*776 + o] = ah[r] + bhs;
            }
        }
    }
    __syncthreads();
    for (int idx = tid; idx < 2048; idx += 768) {
        int s = idx >> 8, j = idx & 255;
        float xr = gx[s*776 + j], xz = gx[s*776 + 256 + j], xn = gx[s*776 + 512 + j];
        float hr = gh[s*776 + j], hz = gh[s*776 + 256 + j], hn = gh[s*776 + 512 + j];
        float r_ = 1.f/(1.f + __expf(-(xr+hr)));
        float z_ = 1.f/(1.f + __expf(-(xz+hz)));
        float n_ = tanhf(xn + r_*hn);
        float pv = slots_in[(size_t)(b*8 + s)*256 + j];
        snew[s*256 + j] = (1.f - z_)*n_ + z_*pv;
    }
    __syncthreads();
    if (wid < 8) {
        int rr = wid;
        float4 v = reinterpret_cast<const float4*>(&snew[rr*256])[lane];
        float s = v.x + v.y + v.z + v.w;
        float ss = v.x*v.x + v.y*v.y + v.z*v.z + v.w*v.w;
#pragma unroll
        for (int off = 32; off >= 1; off >>= 1) { s += __shfl_xor(s, off, 64); ss += __shfl_xor(ss, off, 64); }
        float mean = s * (1.f/256.f);
        float rstd = rsqrtf(ss * (1.f/256.f) - mean*mean + 1e-5f);
        float4 g4 = reinterpret_cast<const float4*>(gff)[lane];
        float4 b4 = reinterpret_cast<const float4*>(bff)[lane];
        ushort4 o;
        o.x = f2bf((v.x-mean)*rstd*g4.x + b4.x);
        o.y = f2bf((v.y-mean)*rstd*g4.y + b4.y);
        o.z = f2bf((v.z-mean)*rstd*g4.z + b4.z);
        o.w = f2bf((v.w-mean)*rstd*g4.w + b4.w);
        *reinterpret_cast<ushort4*>(&lnb[rr*264 + lane*4]) = o;
    } else {
        ushort4 z = {0,0,0,0};
        *reinterpret_cast<ushort4*>(&lnb[wid*264 + lane*4]) = z;
        *reinterpret_cast<ushort4*>(&lnb[(wid+4)*264 + lane*4]) = z;
    }
    __syncthreads();
    short8 al[8];
#pragma unroll
    for (int k = 0; k < 8; k++) al[k] = *reinterpret_cast<const short8*>(&lnb[l15*264 + k*32 + kq]);
    for (int ct = wid; ct < 16; ct += 12) {
        int o0 = ct*16;
        f32x4 a = (f32x4){0.f,0.f,0.f,0.f};
#pragma unroll
        for (int k = 0; k < 8; k++) {
            short8 bw = *reinterpret_cast<const short8*>(&w1b[(size_t)(o0 + l15)*256 + k*32 + kq]);
            a = mfma16(al[k], bw, a);
        }
        if (lane < 32) {
            int sb = (lane >> 4)*4, o = o0 + l15;
            float bb = b1v[o];
#pragma unroll
            for (int r = 0; r < 4; r++)
                updb[(sb+r)*264 + o] = f2bf(fmaxf(a[r] + bb, 0.f));
        }
    }
    __syncthreads();
    short8 ah2[8];
#pragma unroll
    for (int k = 0; k < 8; k++) ah2[k] = *reinterpret_cast<const short8*>(&updb[l15*264 + k*32 + kq]);
    for (int ct = wid; ct < 16; ct += 12) {
        int o0 = ct*16;
        f32x4 a = (f32x4){0.f,0.f,0.f,0.f};
#pragma unroll
        for (int k = 0; k < 8; k++) {
            short8 bw = *reinterpret_cast<const short8*>(&w2b[(size_t)(o0 + l15)*256 + k*32 + kq]);
            a = mfma16(ah2[k], bw, a);
        }
        if (lane < 32) {
            int sb = (lane >> 4)*4, o = o0 + l15;
            float bb = b2v[o];
#pragma unroll
            for (int r = 0; r < 4; r++)
                slots_out[(size_t)(b*8 + sb + r)*256 + o] = snew[(sb+r)*256 + o] + a[r] + bb;
        }
    }
}

extern "C" void kernel_launch(void* const* d_in, const int* in_sizes, int n_in,
                              void* d_out, int out_size, void* d_ws, size_t ws_size,
                              hipStream_t stream) {
    (void)in_sizes; (void)n_in; (void)out_size;
    const float* inputs     = (const float*)d_in[0];
    const float* init_slots = (const float*)d_in[1];
    const float* wq  = (const float*)d_in[2];
    const float* bq  = (const float*)d_in[3];
    const float* wk  = (const float*)d_in[4];
    const float* bk  = (const float*)d_in[5];
    const float* wv  = (const float*)d_in[6];
    const float* bv  = (const float*)d_in[7];
    const float* wih = (const float*)d_in[8];
    const float* bih = (const float*)d_in[9];
    const float* whh = (const float*)d_in[10];
    const float* bhh = (const float*)d_in[11];
    const float* w1  = (const float*)d_in[12];
    const float* b1  = (const float*)d_in[13];
    const float* w2  = (const float*)d_in[14];
    const float* b2  = (const float*)d_in[15];
    const float* g_in = (const float*)d_in[16];
    const float* b_in = (const float*)d_in[17];
    const float* g_sl = (const float*)d_in[18];
    const float* b_sl = (const float*)d_in[19];
    const float* g_ff = (const float*)d_in[20];
    const float* b_ff = (const float*)d_in[21];

    char* ws = (char*)d_ws;
    size_t off = 0;
    auto alloc = [&](size_t bytes) -> void* {
        void* p = ws + off;
        off += (bytes + 255) & ~(size_t)255;
        return p;
    };
    u16* xb    = (u16*)alloc((size_t)GROWS * ND * 2);   // LN(inputs) bf16
    u16* kbf   = (u16*)alloc((size_t)GROWS * ND * 2);   // k bf16 [b][n][d]
    u16* vTb   = (u16*)alloc((size_t)GROWS * ND * 2);   // v bf16 transposed [b][d][n]
    u16* qbf   = (u16*)alloc((size_t)NB * NS * ND * 2);
    float* slots = (float*)alloc((size_t)NB * NS * ND * 4);
    float* numb  = (float*)alloc((size_t)NB * NS * ND * 4);  // 524288 B (256-aligned)
    float* denb  = (float*)alloc((size_t)NB * NS * 4);       // contiguous after numb
    u16* wkvb = (u16*)alloc(131072 * 2);
    u16* wqb  = (u16*)alloc(65536 * 2);
    u16* wihb = (u16*)alloc(196608 * 2);
    u16* whhb = (u16*)alloc(196608 * 2);
    u16* w1b  = (u16*)alloc(65536 * 2);
    u16* w2b  = (u16*)alloc(65536 * 2);
    if (off > ws_size) return;  // insufficient workspace -> visible failure

    prep_w<<<2816, 256, 0, stream>>>(wk, wv, wq, wih, whh, w1, w2,
                                     wkvb, wqb, wihb, whhb, w1b, w2b);
    hipMemcpyAsync(slots, init_slots, (size_t)NB * NS * ND * 4,
                   hipMemcpyDeviceToDevice, stream);
    ln_x<<<GROWS / 4, 256, 0, stream>>>(inputs, g_in, b_in, xb);
    gemm_kv<<<(GROWS / 128) * 4, 256, 0, stream>>>(xb, wkvb, bk, bv, kbf, vTb);
    for (int it = 0; it < 3; it++) {
        hipMemsetAsync(numb, 0, (size_t)(NB*NS*ND + NB*NS) * 4, stream);
        q_proj<<<NB, 256, 0, stream>>>(slots, wqb, bq, g_sl, b_sl, qbf);
        attn<<<NB * 16, 256, 0, stream>>>(qbf, kbf, vTb, numb, denb);
        float* outp = (it == 2) ? (float*)d_out : slots;
        finalize<<<NB, 768, 0, stream>>>(slots, numb, denb, wihb, bih, whhb, bhh,
                                         w1b, b1, w2b, b2, g_ff, b_ff, outp);
    }
}

// Round 3
// 934.559 us; speedup vs baseline: 1.0333x; 1.0333x over previous
//
#include <hip/hip_runtime.h>
#include <hip/hip_bf16.h>
#include <stdint.h>

typedef unsigned short u16;
typedef __attribute__((ext_vector_type(8))) short short8;
typedef __attribute__((ext_vector_type(4))) float f32x4;

#define NB 64
#define NN 4096
#define NS 8
#define ND 256
#define GROWS (NB*NN)   // 262144

__device__ inline u16 f2bf(float f) {
    uint32_t u = __float_as_uint(f);
    u = (u + 0x7FFFu + ((u >> 16) & 1u)) >> 16;
    return (u16)u;
}
__device__ inline float bf2f(u16 h) {
    return __uint_as_float(((uint32_t)h) << 16);
}
__device__ inline f32x4 mfma16(short8 a, short8 b, f32x4 c) {
    return __builtin_amdgcn_mfma_f32_16x16x32_bf16(a, b, c, 0, 0, 0);
}
// async global->LDS, 16B per lane; LDS dest = wave-uniform base + lane*16
__device__ __forceinline__ void lds_load16(const u16* g, u16* l) {
    __builtin_amdgcn_global_load_lds(
        (const __attribute__((address_space(1))) void*)g,
        (__attribute__((address_space(3))) void*)l,
        16, 0, 0);
}

// ---------------- weight conversion fp32 -> bf16 (once per launch) ----------
__global__ __launch_bounds__(256) void prep_w(
        const float* __restrict__ wk, const float* __restrict__ wv, const float* __restrict__ wq,
        const float* __restrict__ wih, const float* __restrict__ whh,
        const float* __restrict__ w1, const float* __restrict__ w2,
        u16* __restrict__ wkvb, u16* __restrict__ wqb, u16* __restrict__ wihb,
        u16* __restrict__ whhb, u16* __restrict__ w1b, u16* __restrict__ w2b) {
    int i = blockIdx.x * 256 + threadIdx.x;
    if (i < 131072) { wkvb[i] = f2bf(i < 65536 ? wk[i] : wv[i - 65536]); return; }
    i -= 131072;
    if (i < 65536) { wqb[i] = f2bf(wq[i]); return; }
    i -= 65536;
    if (i < 196608) { wihb[i] = f2bf(wih[i]); return; }
    i -= 196608;
    if (i < 196608) { whhb[i] = f2bf(whh[i]); return; }
    i -= 196608;
    if (i < 65536) { w1b[i] = f2bf(w1[i]); return; }
    i -= 65536;
    w2b[i] = f2bf(w2[i]);
}

// ---------------- LayerNorm(inputs) -> x bf16 -------------------------------
__global__ __launch_bounds__(256) void ln_x(
        const float* __restrict__ inp, const float* __restrict__ g,
        const float* __restrict__ bt, u16* __restrict__ xb) {
    int row = blockIdx.x * 4 + (threadIdx.x >> 6);
    int lane = threadIdx.x & 63;
    float4 v = reinterpret_cast<const float4*>(inp + (size_t)row * ND)[lane];
    float s = v.x + v.y + v.z + v.w;
    float ss = v.x*v.x + v.y*v.y + v.z*v.z + v.w*v.w;
#pragma unroll
    for (int off = 32; off >= 1; off >>= 1) { s += __shfl_xor(s, off, 64); ss += __shfl_xor(ss, off, 64); }
    float mean = s * (1.0f/256.0f);
    float rstd = rsqrtf(ss * (1.0f/256.0f) - mean*mean + 1e-5f);
    float4 g4 = reinterpret_cast<const float4*>(g)[lane];
    float4 b4 = reinterpret_cast<const float4*>(bt)[lane];
    ushort4 o;
    o.x = f2bf((v.x-mean)*rstd*g4.x + b4.x);
    o.y = f2bf((v.y-mean)*rstd*g4.y + b4.y);
    o.z = f2bf((v.z-mean)*rstd*g4.z + b4.z);
    o.w = f2bf((v.w-mean)*rstd*g4.w + b4.w);
    *reinterpret_cast<ushort4*>(xb + (size_t)row * ND + lane*4) = o;
}

// ---------------- K/V projection GEMM: C = x @ [wk|wv]^T --------------------
// cols 0..255 -> k (row-major bf16), cols 256..511 -> vT[b][d][n] bf16
// m97-style: global_load_lds(16B) staging, XOR swizzle on global side, BK=64.
__global__ __launch_bounds__(256) void gemm_kv(
        const u16* __restrict__ A, const u16* __restrict__ W,
        const float* __restrict__ bk, const float* __restrict__ bv,
        u16* __restrict__ kout, u16* __restrict__ vT) {
    __shared__ u16 smem[17408];            // 34816 B union: As(16K)+Bs(16K) | Ct(34K)
    u16* As = smem;                         // [128][64] row-major, swizzled blocks
    u16* Bs = smem + 8192;
    const int bx = blockIdx.x;
    const int nt = bx & 3;
    const long r0 = (long)(bx >> 2) * 128;
    const int o0 = nt * 128;
    const int tid = threadIdx.x;
    const int wid = tid >> 6, lane = tid & 63;
    const int l15 = lane & 15, kq8 = lane >> 4, kq = kq8 * 8;
    const int wm = (wid >> 1) * 64, wn = (wid & 1) * 64;
    // staging lane geometry: 8 rows x 128B per wave-inst; swizzle global k-block
    const int srow = lane >> 3;                       // 0..7
    const int sblk = (lane & 7) ^ srow;               // 16B block 0..7 (xor swizzle)
    f32x4 acc[4][4];
#pragma unroll
    for (int i = 0; i < 4; i++)
#pragma unroll
        for (int j = 0; j < 4; j++) acc[i][j] = (f32x4){0.f,0.f,0.f,0.f};

    const u16* Ag = &A[(r0 + wid*8 + srow)*256 + sblk*8];
    const u16* Wg = &W[(long)(o0 + wid*8 + srow)*256 + sblk*8];
    u16* AsW = &As[(wid*8)*64];   // wave-uniform LDS base
    u16* BsW = &Bs[(wid*8)*64];

    for (int k0 = 0; k0 < 256; k0 += 64) {
        __syncthreads();
#pragma unroll
        for (int j = 0; j < 4; j++) {
            lds_load16(Ag + (j*32)*256 + k0, AsW + (j*32)*64);
            lds_load16(Wg + (j*32)*256 + k0, BsW + (j*32)*64);
        }
        __syncthreads();   // drains vmcnt (global_load_lds) + visibility
        short8 af[2][4], bfr[2][4];
#pragma unroll
        for (int ks = 0; ks < 2; ks++) {
            const int ca = ((ks*4 + kq8) ^ (l15 & 7)) * 8;  // un-swizzle
#pragma unroll
            for (int i = 0; i < 4; i++) {
                af[ks][i]  = *reinterpret_cast<const short8*>(&As[(wm + i*16 + l15)*64 + ca]);
                bfr[ks][i] = *reinterpret_cast<const short8*>(&Bs[(wn + i*16 + l15)*64 + ca]);
            }
        }
#pragma unroll
        for (int i = 0; i < 4; i++)
#pragma unroll
            for (int j = 0; j < 4; j++) {
                acc[i][j] = mfma16(af[0][i], bfr[0][j], acc[i][j]);
                acc[i][j] = mfma16(af[1][i], bfr[1][j], acc[i][j]);
            }
    }
    __syncthreads();       // before reusing smem as Ct
    u16* Ct = smem;        // [128][136]
    if (nt < 2) {
        // k output, row-major: repack through LDS then coalesced 16B stores
#pragma unroll
        for (int i = 0; i < 4; i++)
#pragma unroll
            for (int j = 0; j < 4; j++) {
                int c = wn + j*16 + l15;
                float bb = bk[o0 + c];
                int mb = wm + i*16 + kq8*4;
#pragma unroll
                for (int r = 0; r < 4; r++)
                    Ct[(mb + r)*136 + c] = f2bf(acc[i][j][r] + bb);
            }
        __syncthreads();
        int rr = tid >> 1, cc = (tid & 1) * 64;
#pragma unroll
        for (int u = 0; u < 64; u += 8)
            *reinterpret_cast<short8*>(&kout[(r0 + rr)*256 + o0 + cc + u]) =
                *reinterpret_cast<const short8*>(&Ct[rr*136 + cc + u]);
    } else {
        // v output, transposed to vT[b][d][n]
#pragma unroll
        for (int i = 0; i < 4; i++)
#pragma unroll
            for (int j = 0; j < 4; j++) {
                int c = wn + j*16 + l15;
                float bb = bv[o0 - 256 + c];
                int mb = wm + i*16 + kq8*4;
                ushort4 pk;
                pk.x = f2bf(acc[i][j][0] + bb);
                pk.y = f2bf(acc[i][j][1] + bb);
                pk.z = f2bf(acc[i][j][2] + bb);
                pk.w = f2bf(acc[i][j][3] + bb);
                *reinterpret_cast<ushort4*>(&Ct[c*136 + mb]) = pk;
            }
        __syncthreads();
        int rr = tid >> 1, cc = (tid & 1) * 64;
        long b_ = r0 >> 12;
        long n0_ = r0 & 4095;
        long dg = (o0 - 256) + rr;
#pragma unroll
        for (int u = 0; u < 64; u += 8)
            *reinterpret_cast<short8*>(&vT[(b_*256 + dg)*4096 + n0_ + cc + u]) =
                *reinterpret_cast<const short8*>(&Ct[rr*136 + cc + u]);
    }
}

// ---------------- q projection (iteration 0 only) ---------------------------
__global__ __launch_bounds__(256) void q_proj(
        const float* __restrict__ slots, const u16* __restrict__ wqb,
        const float* __restrict__ bq, const float* __restrict__ gs, const float* __restrict__ bs,
        u16* __restrict__ qb) {
    __shared__ u16 sn[16*264];
    const int b = blockIdx.x;
    const int tid = threadIdx.x, wid = tid >> 6, lane = tid & 63;
    const int l15 = lane & 15, kq = (lane >> 4) * 8;
    for (int rr = wid; rr < 8; rr += 4) {
        float4 v = reinterpret_cast<const float4*>(slots + (size_t)(b*8 + rr)*256)[lane];
        float s = v.x + v.y + v.z + v.w;
        float ss = v.x*v.x + v.y*v.y + v.z*v.z + v.w*v.w;
#pragma unroll
        for (int off = 32; off >= 1; off >>= 1) { s += __shfl_xor(s, off, 64); ss += __shfl_xor(ss, off, 64); }
        float mean = s * (1.f/256.f);
        float rstd = rsqrtf(ss * (1.f/256.f) - mean*mean + 1e-5f);
        float4 g4 = reinterpret_cast<const float4*>(gs)[lane];
        float4 b4 = reinterpret_cast<const float4*>(bs)[lane];
        ushort4 o;
        o.x = f2bf((v.x-mean)*rstd*g4.x + b4.x);
        o.y = f2bf((v.y-mean)*rstd*g4.y + b4.y);
        o.z = f2bf((v.z-mean)*rstd*g4.z + b4.z);
        o.w = f2bf((v.w-mean)*rstd*g4.w + b4.w);
        *reinterpret_cast<ushort4*>(&sn[rr*264 + lane*4]) = o;
    }
    {
        ushort4 z = {0,0,0,0};
        for (int rr = 8 + wid; rr < 16; rr += 4)
            *reinterpret_cast<ushort4*>(&sn[rr*264 + lane*4]) = z;
    }
    __syncthreads();
    short8 af[8];
#pragma unroll
    for (int k = 0; k < 8; k++) af[k] = *reinterpret_cast<const short8*>(&sn[l15*264 + k*32 + kq]);
#pragma unroll
    for (int ct = 0; ct < 4; ct++) {
        int o0 = (wid*4 + ct)*16;
        f32x4 a = (f32x4){0.f,0.f,0.f,0.f};
#pragma unroll
        for (int k = 0; k < 8; k++) {
            short8 bw = *reinterpret_cast<const short8*>(&wqb[(size_t)(o0 + l15)*256 + k*32 + kq]);
            a = mfma16(af[k], bw, a);
        }
        if (lane < 32) {
            int sb = (lane >> 4)*4;
            float bb = bq[o0 + l15];
#pragma unroll
            for (int r = 0; r < 4; r++)
                qb[(size_t)(b*8 + sb + r)*256 + o0 + l15] = f2bf(a[r] + bb);
        }
    }
}

// ---------------- fused attention pass: dots -> softmax(S) -> P.V partials --
// 1 barrier/round (double-buffered p_lds), v+k prefetched ahead of the barrier
__global__ __launch_bounds__(256) void attn(
        const u16* __restrict__ qb, const u16* __restrict__ kb,
        const u16* __restrict__ vT, float* __restrict__ num, float* __restrict__ den) {
    __shared__ u16 q_lds[16*264];
    __shared__ u16 p_lds[2][16*72];
    const int b = blockIdx.x >> 4;
    const int n0 = (blockIdx.x & 15) * 256;
    const int tid = threadIdx.x, wid = tid >> 6, lane = tid & 63;
    const int l15 = lane & 15, kq = (lane >> 4) * 8;
    {
        int rr = tid >> 5, c8 = (tid & 31) * 8;
        *reinterpret_cast<short8*>(&q_lds[rr*264 + c8]) =
            *reinterpret_cast<const short8*>(&qb[(size_t)(b*8 + rr)*256 + c8]);
        short8 z = {0,0,0,0,0,0,0,0};
        *reinterpret_cast<short8*>(&q_lds[(8 + rr)*264 + c8]) = z;
    }
    // zero pad rows 8..15 of both p buffers
    for (int z4 = tid; z4 < 288; z4 += 256) {
        int buf = z4 / 144, w = z4 % 144;
        int r8 = 8 + w/18, c4 = (w%18)*4;
        ushort4 zz = {0,0,0,0};
        *reinterpret_cast<ushort4*>(&p_lds[buf][r8*72 + c4]) = zz;
    }
    __syncthreads();
    short8 aq[8];
#pragma unroll
    for (int k = 0; k < 8; k++) aq[k] = *reinterpret_cast<const short8*>(&q_lds[l15*264 + k*32 + kq]);
    const u16* kbase = &kb[((size_t)b*4096 + n0 + wid*16 + l15)*256 + kq];
    const u16* vbase = &vT[((size_t)b*256 + wid*64 + l15)*4096 + n0 + kq];
    short8 kf[8], kn[8];
#pragma unroll
    for (int k = 0; k < 8; k++) kf[k] = *reinterpret_cast<const short8*>(&kbase[k*32]);
    f32x4 acc[4];
#pragma unroll
    for (int dt = 0; dt < 4; dt++) acc[dt] = (f32x4){0.f,0.f,0.f,0.f};
    float psum[4] = {0.f,0.f,0.f,0.f};
    for (int rnd = 0; rnd < 4; rnd++) {
        const int nboff = rnd*64;
        // prefetch v fragments for this round (independent of p)
        short8 vf[4][2];
#pragma unroll
        for (int dt = 0; dt < 4; dt++) {
            const u16* vr = vbase + (size_t)(dt*16)*4096 + nboff;
            vf[dt][0] = *reinterpret_cast<const short8*>(vr);
            vf[dt][1] = *reinterpret_cast<const short8*>(vr + 32);
        }
        f32x4 dots = (f32x4){0.f,0.f,0.f,0.f};
#pragma unroll
        for (int k = 0; k < 8; k++) dots = mfma16(aq[k], kf[k], dots);
        // prefetch next round's k behind the dots chain
        if (rnd < 3) {
#pragma unroll
            for (int k = 0; k < 8; k++)
                kn[k] = *reinterpret_cast<const short8*>(&kbase[(size_t)(rnd+1)*64*256 + k*32]);
        }
        float t0 = dots[0]*0.0625f, t1 = dots[1]*0.0625f, t2 = dots[2]*0.0625f, t3 = dots[3]*0.0625f;
        float m4 = fmaxf(fmaxf(t0,t1), fmaxf(t2,t3));
        float m8 = fmaxf(m4, __shfl_xor(m4, 16, 64));
        float e0 = __expf(t0-m8), e1 = __expf(t1-m8), e2 = __expf(t2-m8), e3 = __expf(t3-m8);
        float s4 = e0+e1+e2+e3;
        float s8 = s4 + __shfl_xor(s4, 16, 64);
        float inv = 1.0f / s8;
        u16 h0 = f2bf(e0*inv + 1e-8f);
        u16 h1 = f2bf(e1*inv + 1e-8f);
        u16 h2 = f2bf(e2*inv + 1e-8f);
        u16 h3 = f2bf(e3*inv + 1e-8f);
        u16* pb = (u16*)p_lds[rnd & 1];
        if (lane < 32) {
            int sb = (lane >> 4)*4;
            int col = wid*16 + l15;
            pb[(sb+0)*72 + col] = h0;
            pb[(sb+1)*72 + col] = h1;
            pb[(sb+2)*72 + col] = h2;
            pb[(sb+3)*72 + col] = h3;
            psum[0] += bf2f(h0); psum[1] += bf2f(h1);
            psum[2] += bf2f(h2); psum[3] += bf2f(h3);
        }
        __syncthreads();
        short8 ap0 = *reinterpret_cast<const short8*>(&pb[l15*72 + kq]);
        short8 ap1 = *reinterpret_cast<const short8*>(&pb[l15*72 + 32 + kq]);
#pragma unroll
        for (int dt = 0; dt < 4; dt++) {
            acc[dt] = mfma16(ap0, vf[dt][0], acc[dt]);
            acc[dt] = mfma16(ap1, vf[dt][1], acc[dt]);
        }
        if (rnd < 3) {
#pragma unroll
            for (int k = 0; k < 8; k++) kf[k] = kn[k];
        }
    }
#pragma unroll
    for (int off = 1; off < 16; off <<= 1) {
#pragma unroll
        for (int r = 0; r < 4; r++) psum[r] += __shfl_xor(psum[r], off, 64);
    }
    if (lane < 32) {
        int sb = (lane >> 4)*4;
        if (l15 == 0) {
#pragma unroll
            for (int r = 0; r < 4; r++) atomicAdd(&den[b*8 + sb + r], psum[r]);
        }
#pragma unroll
        for (int dt = 0; dt < 4; dt++) {
            int d0 = wid*64 + dt*16 + l15;
#pragma unroll
            for (int r = 0; r < 4; r++)
                atomicAdd(&num[((size_t)b*8 + sb + r)*256 + d0], acc[dt][r]);
        }
    }
}

// ---------------- per-iteration tail: updates -> GRU -> MLP -> slots (+q) ---
__global__ __launch_bounds__(768) void finalize(
        const float* __restrict__ slots_in, const float* __restrict__ num, const float* __restrict__ den,
        const u16* __restrict__ wihb, const float* __restrict__ bih,
        const u16* __restrict__ whhb, const float* __restrict__ bhh,
        const u16* __restrict__ w1b, const float* __restrict__ b1v,
        const u16* __restrict__ w2b, const float* __restrict__ b2v,
        const float* __restrict__ gff, const float* __restrict__ bff,
        float* __restrict__ slots_out,
        const u16* __restrict__ wqb, const float* __restrict__ bq,
        const float* __restrict__ gs, const float* __restrict__ bs,
        u16* __restrict__ qb, int do_q) {
    __shared__ u16 updb[16*264];
    __shared__ u16 prevb[16*264];
    __shared__ u16 lnb[16*264];
    __shared__ float gx[8*776];
    __shared__ float gh[8*776];
    __shared__ float snew[8*256];
    float* sfin = gx;    // reuse after gates consumed
    const int b = blockIdx.x;
    const int tid = threadIdx.x, wid = tid >> 6, lane = tid & 63;
    const int l15 = lane & 15, kq = (lane >> 4) * 8;
    for (int idx = tid; idx < 2048; idx += 768) {
        int s = idx >> 8, d = idx & 255;
        updb[s*264 + d] = f2bf(num[(size_t)(b*8 + s)*256 + d] / den[b*8 + s]);
        prevb[s*264 + d] = f2bf(slots_in[(size_t)(b*8 + s)*256 + d]);
        updb[(8+s)*264 + d] = 0;
        prevb[(8+s)*264 + d] = 0;
    }
    __syncthreads();
    short8 au[8], ap[8];
#pragma unroll
    for (int k = 0; k < 8; k++) {
        au[k] = *reinterpret_cast<const short8*>(&updb[l15*264 + k*32 + kq]);
        ap[k] = *reinterpret_cast<const short8*>(&prevb[l15*264 + k*32 + kq]);
    }
#pragma unroll
    for (int ct = 0; ct < 4; ct++) {
        int o0 = (wid*4 + ct)*16;
        f32x4 ax = (f32x4){0.f,0.f,0.f,0.f}, ah = (f32x4){0.f,0.f,0.f,0.f};
#pragma unroll
        for (int k = 0; k < 8; k++) {
            short8 bx = *reinterpret_cast<const short8*>(&wihb[(size_t)(o0 + l15)*256 + k*32 + kq]);
            short8 bh = *reinterpret_cast<const short8*>(&whhb[(size_t)(o0 + l15)*256 + k*32 + kq]);
            ax = mfma16(au[k], bx, ax);
            ah = mfma16(ap[k], bh, ah);
        }
        if (lane < 32) {
            int sb = (lane >> 4)*4, o = o0 + l15;
            float bxs = bih[o], bhs = bhh[o];
#pragma unroll
            for (int r = 0; r < 4; r++) {
                gx[(sb+r)*776 + o] = ax[r] + bxs;
                gh[(sb+r)*776 + o] = ah[r] + bhs;
            }
        }
    }
    __syncthreads();
    for (int idx = tid; idx < 2048; idx += 768) {
        int s = idx >> 8, j = idx & 255;
        float xr = gx[s*776 + j], xz = gx[s*776 + 256 + j], xn = gx[s*776 + 512 + j];
        float hr = gh[s*776 + j], hz = gh[s*776 + 256 + j], hn = gh[s*776 + 512 + j];
        float r_ = 1.f/(1.f + __expf(-(xr+hr)));
        float z_ = 1.f/(1.f + __expf(-(xz+hz)));
        float n_ = tanhf(xn + r_*hn);
        float pv = slots_in[(size_t)(b*8 + s)*256 + j];
        snew[s*256 + j] = (1.f - z_)*n_ + z_*pv;
    }
    __syncthreads();
    if (wid < 8) {
        int rr = wid;
        float4 v = reinterpret_cast<const float4*>(&snew[rr*256])[lane];
        float s = v.x + v.y + v.z + v.w;
        float ss = v.x*v.x + v.y*v.y + v.z*v.z + v.w*v.w;
#pragma unroll
        for (int off = 32; off >= 1; off >>= 1) { s += __shfl_xor(s, off, 64); ss += __shfl_xor(ss, off, 64); }
        float mean = s * (1.f/256.f);
        float rstd = rsqrtf(ss * (1.f/256.f) - mean*mean + 1e-5f);
        float4 g4 = reinterpret_cast<const float4*>(gff)[lane];
        float4 b4 = reinterpret_cast<const float4*>(bff)[lane];
        ushort4 o;
        o.x = f2bf((v.x-mean)*rstd*g4.x + b4.x);
        o.y = f2bf((v.y-mean)*rstd*g4.y + b4.y);
        o.z = f2bf((v.z-mean)*rstd*g4.z + b4.z);
        o.w = f2bf((v.w-mean)*rstd*g4.w + b4.w);
        *reinterpret_cast<ushort4*>(&lnb[rr*264 + lane*4]) = o;
    } else {
        ushort4 z = {0,0,0,0};
        *reinterpret_cast<ushort4*>(&lnb[wid*264 + lane*4]) = z;
        *reinterpret_cast<ushort4*>(&lnb[(wid+4)*264 + lane*4]) = z;
    }
    __syncthreads();
    short8 al[8];
#pragma unroll
    for (int k = 0; k < 8; k++) al[k] = *reinterpret_cast<const short8*>(&lnb[l15*264 + k*32 + kq]);
    for (int ct = wid; ct < 16; ct += 12) {
        int o0 = ct*16;
        f32x4 a = (f32x4){0.f,0.f,0.f,0.f};
#pragma unroll
        for (int k = 0; k < 8; k++) {
            short8 bw = *reinterpret_cast<const short8*>(&w1b[(size_t)(o0 + l15)*256 + k*32 + kq]);
            a = mfma16(al[k], bw, a);
        }
        if (lane < 32) {
            int sb = (lane >> 4)*4, o = o0 + l15;
            float bb = b1v[o];
#pragma unroll
            for (int r = 0; r < 4; r++)
                updb[(sb+r)*264 + o] = f2bf(fmaxf(a[r] + bb, 0.f));
        }
    }
    __syncthreads();
    short8 ah2[8];
#pragma unroll
    for (int k = 0; k < 8; k++) ah2[k] = *reinterpret_cast<const short8*>(&updb[l15*264 + k*32 + kq]);
    for (int ct = wid; ct < 16; ct += 12) {
        int o0 = ct*16;
        f32x4 a = (f32x4){0.f,0.f,0.f,0.f};
#pragma unroll
        for (int k = 0; k < 8; k++) {
            short8 bw = *reinterpret_cast<const short8*>(&w2b[(size_t)(o0 + l15)*256 + k*32 + kq]);
            a = mfma16(ah2[k], bw, a);
        }
        if (lane < 32) {
            int sb = (lane >> 4)*4, o = o0 + l15;
            float bb = b2v[o];
#pragma unroll
            for (int r = 0; r < 4; r++) {
                float vfin = snew[(sb+r)*256 + o] + a[r] + bb;
                slots_out[(size_t)(b*8 + sb + r)*256 + o] = vfin;
                sfin[(sb+r)*256 + o] = vfin;
            }
        }
    }
    if (!do_q) return;
    __syncthreads();
    // fused q projection for next iteration: q = LN(slots_new)@wq^T + bq
    if (wid < 8) {
        int rr = wid;
        float4 v = reinterpret_cast<const float4*>(&sfin[rr*256])[lane];
        float s = v.x + v.y + v.z + v.w;
        float ss = v.x*v.x + v.y*v.y + v.z*v.z + v.w*v.w;
#pragma unroll
        for (int off = 32; off >= 1; off >>= 1) { s += __shfl_xor(s, off, 64); ss += __shfl_xor(ss, off, 64); }
        float mean = s * (1.f/256.f);
        float rstd = rsqrtf(ss * (1.f/256.f) - mean*mean + 1e-5f);
        float4 g4 = reinterpret_cast<const float4*>(gs)[lane];
        float4 b4 = reinterpret_cast<const float4*>(bs)[lane];
        ushort4 o;
        o.x = f2bf((v.x-mean)*rstd*g4.x + b4.x);
        o.y = f2bf((v.y-mean)*rstd*g4.y + b4.y);
        o.z = f2bf((v.z-mean)*rstd*g4.z + b4.z);
        o.w = f2bf((v.w-mean)*rstd*g4.w + b4.w);
        *reinterpret_cast<ushort4*>(&lnb[rr*264 + lane*4]) = o;
    } else {
        ushort4 z = {0,0,0,0};
        *reinterpret_cast<ushort4*>(&lnb[wid*264 + lane*4]) = z;
        *reinterpret_cast<ushort4*>(&lnb[(wid+4)*264 + lane*4]) = z;
    }
    __syncthreads();
    short8 alq[8];
#pragma unroll
    for (int k = 0; k < 8; k++) alq[k] = *reinterpret_cast<const short8*>(&lnb[l15*264 + k*32 + kq]);
    for (int ct = wid; ct < 16; ct += 12) {
        int o0 = ct*16;
        f32x4 a = (f32x4){0.f,0.f,0.f,0.f};
#pragma unroll
        for (int k = 0; k < 8; k++) {
            short8 bw = *reinterpret_cast<const short8*>(&wqb[(size_t)(o0 + l15)*256 + k*32 + kq]);
            a = mfma16(alq[k], bw, a);
        }
        if (lane < 32) {
            int sb = (lane >> 4)*4, o = o0 + l15;
            float bb = bq[o];
#pragma unroll
            for (int r = 0; r < 4; r++)
                qb[(size_t)(b*8 + sb + r)*256 + o] = f2bf(a[r] + bb);
        }
    }
}

extern "C" void kernel_launch(void* const* d_in, const int* in_sizes, int n_in,
                              void* d_out, int out_size, void* d_ws, size_t ws_size,
                              hipStream_t stream) {
    (void)in_sizes; (void)n_in; (void)out_size;
    const float* inputs     = (const float*)d_in[0];
    const float* init_slots = (const float*)d_in[1];
    const float* wq  = (const float*)d_in[2];
    const float* bq  = (const float*)d_in[3];
    const float* wk  = (const float*)d_in[4];
    const float* bk  = (const float*)d_in[5];
    const float* wv  = (const float*)d_in[6];
    const float* bv  = (const float*)d_in[7];
    const float* wih = (const float*)d_in[8];
    const float* bih = (const float*)d_in[9];
    const float* whh = (const float*)d_in[10];
    const float* bhh = (const float*)d_in[11];
    const float* w1  = (const float*)d_in[12];
    const float* b1  = (const float*)d_in[13];
    const float* w2  = (const float*)d_in[14];
    const float* b2  = (const float*)d_in[15];
    const float* g_in = (const float*)d_in[16];
    const float* b_in = (const float*)d_in[17];
    const float* g_sl = (const float*)d_in[18];
    const float* b_sl = (const float*)d_in[19];
    const float* g_ff = (const float*)d_in[20];
    const float* b_ff = (const float*)d_in[21];

    char* ws = (char*)d_ws;
    size_t off = 0;
    auto alloc = [&](size_t bytes) -> void* {
        void* p = ws + off;
        off += (bytes + 255) & ~(size_t)255;
        return p;
    };
    u16* xb    = (u16*)alloc((size_t)GROWS * ND * 2);   // LN(inputs) bf16
    u16* kbf   = (u16*)alloc((size_t)GROWS * ND * 2);   // k bf16 [b][n][d]
    u16* vTb   = (u16*)alloc((size_t)GROWS * ND * 2);   // v bf16 transposed [b][d][n]
    u16* qbf   = (u16*)alloc((size_t)NB * NS * ND * 2);
    float* slots = (float*)alloc((size_t)NB * NS * ND * 4);
    float* numb  = (float*)alloc((size_t)NB * NS * ND * 4);  // + den contiguous
    float* denb  = (float*)alloc((size_t)NB * NS * 4);
    u16* wkvb = (u16*)alloc(131072 * 2);
    u16* wqb  = (u16*)alloc(65536 * 2);
    u16* wihb = (u16*)alloc(196608 * 2);
    u16* whhb = (u16*)alloc(196608 * 2);
    u16* w1b  = (u16*)alloc(65536 * 2);
    u16* w2b  = (u16*)alloc(65536 * 2);
    if (off > ws_size) return;  // insufficient workspace -> visible failure

    prep_w<<<2816, 256, 0, stream>>>(wk, wv, wq, wih, whh, w1, w2,
                                     wkvb, wqb, wihb, whhb, w1b, w2b);
    hipMemcpyAsync(slots, init_slots, (size_t)NB * NS * ND * 4,
                   hipMemcpyDeviceToDevice, stream);
    ln_x<<<GROWS / 4, 256, 0, stream>>>(inputs, g_in, b_in, xb);
    gemm_kv<<<(GROWS / 128) * 4, 256, 0, stream>>>(xb, wkvb, bk, bv, kbf, vTb);
    q_proj<<<NB, 256, 0, stream>>>(slots, wqb, bq, g_sl, b_sl, qbf);
    for (int it = 0; it < 3; it++) {
        hipMemsetAsync(numb, 0, (size_t)(NB*NS*ND + NB*NS) * 4, stream);
        attn<<<NB * 16, 256, 0, stream>>>(qbf, kbf, vTb, numb, denb);
        float* outp = (it == 2) ? (float*)d_out : slots;
        finalize<<<NB, 768, 0, stream>>>(slots, numb, denb, wihb, bih, whhb, bhh,
                                         w1b, b1, w2b, b2, g_ff, b_ff, outp,
                                         wqb, bq, g_sl, b_sl, qbf, (it < 2) ? 1 : 0);
    }
}